// Round 1
// baseline (220.084 us; speedup 1.0000x reference)
//
#include <hip/hip_runtime.h>
#include <math.h>

// SumLayer: out = node_mars with rows nids[g] <- log(sum_c params[pids[g,c]] * exp(element_mars[cids[g,c], :]))
// G=8192 groups, C=64 children, B=128 batch. All f32.

#define C_CHILD 64
#define B_VEC   32          // B/4 float4 columns per row
#define GRP_PER_BLK 8       // 8 groups * 32 lanes = 256 threads

__global__ __launch_bounds__(256) void copy_f4_kernel(const float4* __restrict__ src,
                                                      float4* __restrict__ dst, int n4) {
    int i = blockIdx.x * 256 + threadIdx.x;
    if (i < n4) dst[i] = src[i];
}

__global__ __launch_bounds__(256) void sum_layer_kernel(
    const float* __restrict__ element_mars,
    const float* __restrict__ params,
    const int*  __restrict__ nids,
    const int*  __restrict__ cids,
    const int*  __restrict__ pids,
    float*      __restrict__ out,
    int G)
{
    __shared__ int   s_cid[GRP_PER_BLK * C_CHILD];
    __shared__ float s_w  [GRP_PER_BLK * C_CHILD];

    const int tid = threadIdx.x;
    const int g0  = blockIdx.x * GRP_PER_BLK;

    // Stage cids and gathered weights for this block's 8 groups (512 each).
    {
        const int base = g0 * C_CHILD;
        int i0 = tid, i1 = tid + 256;
        int c0 = cids[base + i0];
        int c1 = cids[base + i1];
        int p0 = pids[base + i0];
        int p1 = pids[base + i1];
        s_cid[i0] = c0;
        s_cid[i1] = c1;
        s_w[i0] = params[p0];
        s_w[i1] = params[p1];
    }
    __syncthreads();

    const int sub  = tid >> 5;   // group within block [0,8)
    const int lane = tid & 31;   // float4 column [0,32)
    const int g    = g0 + sub;
    if (g >= G) return;

    const float4* em4 = (const float4*)element_mars;

    float4 m = make_float4(-INFINITY, -INFINITY, -INFINITY, -INFINITY);
    float4 s = make_float4(0.f, 0.f, 0.f, 0.f);

    // Online weighted logsumexp, 1 exp per element:
    //   d = x - m; e = exp(-|d|)
    //   d > 0:  s = s*e + w ; m = x
    //   d <= 0: s = w*e + s
#define UPD(comp)                                              \
    {                                                          \
        float d  = x.comp - m.comp;                            \
        float e  = __expf(-fabsf(d));                          \
        float hi = (d > 0.f) ? s.comp : w;                     \
        float lo = (d > 0.f) ? w : s.comp;                     \
        s.comp = fmaf(hi, e, lo);                              \
        m.comp = fmaxf(m.comp, x.comp);                        \
    }

    const int cbase = sub * C_CHILD;
#pragma unroll 8
    for (int c = 0; c < C_CHILD; ++c) {
        int   cid = s_cid[cbase + c];
        float w   = s_w[cbase + c];
        float4 x  = em4[(size_t)cid * B_VEC + lane];
        UPD(x) UPD(y) UPD(z) UPD(w)
    }
#undef UPD

    float4 o;
    o.x = __logf(s.x) + m.x;
    o.y = __logf(s.y) + m.y;
    o.z = __logf(s.z) + m.z;
    o.w = __logf(s.w) + m.w;

    int nid = nids[g];
    ((float4*)out)[(size_t)nid * B_VEC + lane] = o;
}

extern "C" void kernel_launch(void* const* d_in, const int* in_sizes, int n_in,
                              void* d_out, int out_size, void* d_ws, size_t ws_size,
                              hipStream_t stream) {
    const float* node_mars    = (const float*)d_in[0];
    const float* element_mars = (const float*)d_in[1];
    const float* params       = (const float*)d_in[2];
    const int*   nids         = (const int*)d_in[3];
    const int*   cids         = (const int*)d_in[4];
    const int*   pids         = (const int*)d_in[5];
    float*       out          = (float*)d_out;

    const int G = in_sizes[3];

    // 1) out <- node_mars (d_out is poisoned before every launch)
    int n4 = out_size / 4;
    copy_f4_kernel<<<(n4 + 255) / 256, 256, 0, stream>>>(
        (const float4*)node_mars, (float4*)out, n4);

    // 2) compute + scatter nids rows (stream-ordered after the copy)
    int nblk = (G + GRP_PER_BLK - 1) / GRP_PER_BLK;
    sum_layer_kernel<<<nblk, 256, 0, stream>>>(
        element_mars, params, nids, cids, pids, out, G);
}